// Round 1
// baseline (4197.099 us; speedup 1.0000x reference)
//
#include <hip/hip_runtime.h>
#include <math.h>

#define T_   32
#define N_   64
#define NL   64
#define E_   128
#define G3   384   // 3*E
#define NE   4
#define CH   64
#define D_   16
#define HW   16
#define RH   64
#define LE   64
#define HD   512
#define A_   16
#define INVN 32
#define KCOLS 9216 // CH*D_*3*3
#define OUTW 663

__device__ __forceinline__ float sigf(float x) { return 1.f/(1.f+expf(-x)); }

// ---------------- prep kernels ----------------

// M[n][l][i] = sum_tok emb_task[lines[n][l][tok]][i]
__global__ __launch_bounds__(128) void k_prep_M(const int* lines, const float* emb_task, float* M) {
    int nl = blockIdx.x;      // n*64 + l
    int i  = threadIdx.x;     // 0..127
    const int* ln = lines + nl*4;
    float s = 0.f;
    #pragma unroll
    for (int t = 0; t < 4; ++t) s += emb_task[ln[t]*E_ + i];
    M[nl*E_ + i] = s;
}

// transposed+quad-packed weights: T4[((dir*32 + k/4)*384 + g)*4 + (k%4)] = w[dir][g*128+k]
__global__ __launch_bounds__(128) void k_prep_T4(const float* wif, const float* wib,
                                                 const float* whf, const float* whb,
                                                 float* wiT4, float* whT4) {
    int g = blockIdx.x % 384, dir = blockIdx.x / 384;
    int k = threadIdx.x;
    const float* wi = dir ? wib : wif;
    const float* wh = dir ? whb : whf;
    int dst = ((dir*32 + (k>>2))*384 + g)*4 + (k&3);
    wiT4[dst] = wi[g*128 + k];
    whT4[dst] = wh[g*128 + k];
}

__global__ __launch_bounds__(128) void k_prep_misc(const int* p0, const float* M, int* p_cur, float* mp) {
    int n = blockIdx.x, i = threadIdx.x;
    int p = p0[n];
    if (i == 0) p_cur[n] = p;
    mp[n*E_ + i] = M[(n*NL + p)*E_ + i];
}

// inv_all[t][n][r] = relu(inv@inv_w + b), pa_all[t][n][r] = sum emb_lower rows
__global__ __launch_bounds__(64) void k_prep_invpa(const float* inv, const float* inv_w, const float* inv_b,
                                                   const int* pa, const float* emb_lower,
                                                   float* inv_all, float* pa_all) {
    int tn = blockIdx.x, r = threadIdx.x;
    const float* iv = inv + tn*INVN;
    float acc = inv_b[r];
    #pragma unroll
    for (int i = 0; i < INVN; ++i) acc += iv[i]*inv_w[i*RH + r];
    inv_all[tn*RH + r] = fmaxf(acc, 0.f);
    const int* pp = pa + tn*4;
    float s = 0.f;
    #pragma unroll
    for (int j = 0; j < 4; ++j) s += emb_lower[pp[j]*LE + r];
    pa_all[tn*LE + r] = s;
}

// giM[dir][n][l][g] = M[n][l] . wi[g] + bi[g]
__global__ __launch_bounds__(384) void k_giM(const float* M, const float* wiT4,
                                             const float* bif, const float* bib, float* giM) {
    int lblk = blockIdx.x, n = blockIdx.y, dir = blockIdx.z;
    int g = threadIdx.x;
    __shared__ float Ml[8][E_];
    for (int idx = g; idx < 8*E_; idx += 384) {
        int r = idx >> 7, k = idx & 127;
        Ml[r][k] = M[(n*NL + lblk*8 + r)*E_ + k];
    }
    __syncthreads();
    float acc[8];
    #pragma unroll
    for (int r = 0; r < 8; ++r) acc[r] = 0.f;
    const float4* W = (const float4*)(wiT4) + dir*32*384;
    for (int kq = 0; kq < 32; ++kq) {
        float4 w = W[kq*384 + g];
        #pragma unroll
        for (int r = 0; r < 8; ++r) {
            float4 h = *(const float4*)&Ml[r][kq*4];
            acc[r] += w.x*h.x + w.y*h.y + w.z*h.z + w.w*h.w;
        }
    }
    float bi = dir ? bib[g] : bif[g];
    #pragma unroll
    for (int r = 0; r < 8; ++r)
        giM[((dir*N_ + n)*NL + lblk*8 + r)*G3 + g] = acc[r] + bi;
}

// GRU over all rolls. grid (pblk 2, n 64, dir 2), 256 thr. 32 sequences per wg.
// thread: i = tid%128 (hidden idx), sb = tid/128 (16 seqs each).
__global__ __launch_bounds__(256) void k_gru(const float* giM, const float* whT4,
                                             const float* bhf, const float* bhb,
                                             const float* beta_w, const float* beta_b,
                                             float* Ball) {
    int pblk = blockIdx.x, n = blockIdx.y, dir = blockIdx.z;
    int tid = threadIdx.x;
    int i = tid & 127;
    int sb = tid >> 7;

    __shared__ float Hs[32][132];
    __shared__ float bw[E_][NE];
    for (int idx = tid; idx < 32*132; idx += 256) ((float*)Hs)[idx] = 0.f;
    for (int idx = tid; idx < E_*NE; idx += 256) ((float*)bw)[idx] = beta_w[idx];
    const float* bh = dir ? bhb : bhf;
    float bhr = bh[i], bhz = bh[128+i], bhn = bh[256+i];
    const float4* W = (const float4*)(whT4) + dir*32*384;
    const float* giBase = giM + (dir*N_ + n)*NL*G3;
    __syncthreads();

    for (int j = 0; j < NL; ++j) {
        float accr[16], accz[16], accn[16];
        #pragma unroll
        for (int s = 0; s < 16; ++s) { accr[s]=bhr; accz[s]=bhz; accn[s]=bhn; }
        #pragma unroll 2
        for (int kq = 0; kq < 32; ++kq) {
            float4 wr = W[kq*384 + i];
            float4 wz = W[kq*384 + 128 + i];
            float4 wn = W[kq*384 + 256 + i];
            #pragma unroll
            for (int s = 0; s < 16; ++s) {
                float4 h = *(const float4*)&Hs[sb*16 + s][kq*4];
                accr[s] += wr.x*h.x + wr.y*h.y + wr.z*h.z + wr.w*h.w;
                accz[s] += wz.x*h.x + wz.y*h.y + wz.z*h.z + wz.w*h.w;
                accn[s] += wn.x*h.x + wn.y*h.y + wn.z*h.z + wn.w*h.w;
            }
        }
        float hnew[16];
        #pragma unroll
        for (int s = 0; s < 16; ++s) {
            int ss = sb*16 + s;
            int p  = pblk*32 + ss;
            int l  = dir ? ((p + 63 - j) & 63) : ((p + j) & 63);
            const float* gi = giBase + l*G3;
            float r  = sigf(gi[i]       + accr[s]);
            float z  = sigf(gi[128+i]   + accz[s]);
            float nn = tanhf(gi[256+i]  + r*accn[s]);
            hnew[s] = (1.f - z)*nn + z*Hs[ss][i];
        }
        __syncthreads();
        #pragma unroll
        for (int s = 0; s < 16; ++s) Hs[sb*16 + s][i] = hnew[s];
        __syncthreads();
        if (tid < 128) {   // beta head for all 32 seqs x 4 e
            int s = tid >> 2, e = tid & 3;
            float acc = 0.f;
            for (int k = 0; k < E_; ++k) acc += Hs[s][k]*bw[k][e];
            float bval = sigf(acc + beta_b[e]);
            int p = pblk*32 + s;
            int j2 = 2*j + dir;   // fwd even, bwd odd
            Ball[((n*NL + p)*128 + j2)*NE + e] = bval;
        }
    }
}

// stick-breaking -> reordered P_final[n][p][j][e]
__global__ __launch_bounds__(64) void k_P(const float* Ball, float* Pall) {
    int np = blockIdx.x;
    int tid = threadIdx.x;
    __shared__ float B[128][NE];
    __shared__ float Pf[128][NE];
    const float* src = Ball + np*128*NE;
    for (int idx = tid; idx < 128*NE; idx += 64) ((float*)B)[idx] = src[idx];
    __syncthreads();
    if (tid < NE) {
        int e = tid;
        float c = 1.f;
        for (int j2 = 0; j2 < 128; ++j2) {
            float bz = (j2 == 0 || j2 == 127) ? 0.f : B[j2][e];
            float bf = (j2 == 127) ? 1.f : bz;
            Pf[j2][e] = bf * c;
            c *= (1.f - bz);
        }
    }
    __syncthreads();
    float* dst = Pall + np*128*NE;
    for (int idx = tid; idx < 128*NE; idx += 64) {
        int j = idx >> 2, e = idx & 3;
        int jf = (j < 64) ? (2*(63 - j) + 1) : (2*(j - 64));
        dst[idx] = Pf[jf][e];
    }
}

// per-step GEMM: kern_buf[n][col] = mp[n] . kernel_w[:,col] + kernel_b[col]
__global__ __launch_bounds__(256) void k_kern(const float* mp, const float* kernel_w,
                                              const float* kernel_b, float* kern_buf) {
    int tid = threadIdx.x;
    int col = blockIdx.x*32 + (tid & 31);
    int rg  = tid >> 5;      // 0..7 (8 n's each)
    __shared__ float ml[E_][68];
    for (int idx = tid; idx < N_*E_; idx += 256) {
        int nn2 = idx >> 7, e = idx & 127;
        ml[e][nn2] = mp[idx];
    }
    __syncthreads();
    float acc[8];
    #pragma unroll
    for (int r = 0; r < 8; ++r) acc[r] = 0.f;
    for (int e = 0; e < E_; ++e) {
        float w = kernel_w[e*KCOLS + col];
        #pragma unroll
        for (int r = 0; r < 8; ++r) acc[r] += ml[e][rg*8 + r]*w;
    }
    float kb = kernel_b[col];
    #pragma unroll
    for (int r = 0; r < 8; ++r)
        kern_buf[(rg*8 + r)*KCOLS + col] = acc[r] + kb;
}

// per-step conv: grid (cg 8, n 64), 256 thr -> h1_buf[n][c]
__global__ __launch_bounds__(256) void k_conv(const float* obs, const float* kern_buf,
                                              const float* conv_bias, float* h1_buf, int t) {
    int cg = blockIdx.x, n = blockIdx.y;
    int tid = threadIdx.x;
    __shared__ float ol[D_][HW][17];
    __shared__ float kl[8*144];
    __shared__ float part[256];
    const float* op = obs + (size_t)(t*N_ + n)*D_*HW*HW;
    for (int idx = tid; idx < D_*HW*HW; idx += 256) {
        int d = idx >> 8, rem = idx & 255;
        ol[d][rem >> 4][rem & 15] = op[idx];
    }
    const float* kp = kern_buf + n*KCOLS + cg*8*144;
    for (int idx = tid; idx < 8*144; idx += 256) kl[idx] = kp[idx];
    __syncthreads();
    int c   = tid >> 5;
    int sub = tid & 31;
    int y   = sub >> 1;
    int x0  = (sub & 1)*8;
    float acc[8];
    #pragma unroll
    for (int xi = 0; xi < 8; ++xi) acc[xi] = 0.f;
    const float* kc = kl + c*144;
    for (int d = 0; d < D_; ++d) {
        #pragma unroll
        for (int ky = 0; ky < 3; ++ky) {
            int yy = y + ky - 1;
            if (yy < 0 || yy >= HW) continue;
            float row[10];
            #pragma unroll
            for (int jx = 0; jx < 10; ++jx) {
                int xx = x0 + jx - 1;
                row[jx] = (xx >= 0 && xx < HW) ? ol[d][yy][xx] : 0.f;
            }
            #pragma unroll
            for (int kx = 0; kx < 3; ++kx) {
                float kv = kc[9*d + 3*ky + kx];
                #pragma unroll
                for (int xi = 0; xi < 8; ++xi)
                    acc[xi] += row[xi + kx]*kv;
            }
        }
    }
    float bc = conv_bias[cg*8 + c];
    float psum = 0.f;
    #pragma unroll
    for (int xi = 0; xi < 8; ++xi) psum += fmaxf(acc[xi] + bc, 0.f);
    part[tid] = psum;
    __syncthreads();
    if (tid < 8) {
        float s = 0.f;
        for (int k2 = 0; k2 < 32; ++k2) s += part[tid*32 + k2];
        h1_buf[n*CH + cg*8 + tid] = s;
    }
}

// per-step heads: grid 64 (n), 256 thr
__global__ __launch_bounds__(256) void k_step2(
    const float* mp_buf, const float* h1_buf, const float* inv_all, const float* pa_all,
    const float* amask, const float* Pall, const float* M,
    const float* zw, const float* zb, const float* aw, const float* ab,
    const float* uw, const float* ub, const float* dw, const float* db,
    const float* cw, const float* cb,
    int* p_cur, float* out, int t) {
    int n = blockIdx.x, tid = threadIdx.x;
    __shared__ float zin[320];
    __shared__ float z1[HD];
    __shared__ float la[A_];
    __shared__ float lu[NE];
    __shared__ float ld2[2];
    __shared__ float uvals[NE];
    __shared__ float dp[128];
    __shared__ float sc[4];
    __shared__ int   si[4];   // 0: p, 2: dg, 3: p_new
    if (tid < E_)            zin[tid] = mp_buf[n*E_ + tid];
    else if (tid < 192)      zin[tid] = h1_buf[n*CH + (tid - E_)];
    else                     zin[tid] = inv_all[(t*N_ + n)*RH + (tid - 192)];
    if (tid < 64)            zin[256 + tid] = pa_all[(t*N_ + n)*LE + tid];
    if (tid == 0) si[0] = p_cur[n];
    __syncthreads();
    size_t ob = ((size_t)t*N_ + n)*OUTW;
    #pragma unroll
    for (int hh = 0; hh < 2; ++hh) {
        int h = tid + hh*256;
        float acc = zb[h];
        for (int i2 = 0; i2 < 320; ++i2) acc += zin[i2]*zw[i2*HD + h];
        float v = fmaxf(acc, 0.f);
        z1[h] = v;
        out[ob + 146 + h] = v;
    }
    __syncthreads();
    if (tid < A_) {
        float acc = ab[tid];
        for (int h = 0; h < HD; ++h) acc += z1[h]*aw[h*A_ + tid];
        la[tid] = acc;
    } else if (tid < A_ + NE) {
        int e = tid - A_;
        float acc = ub[e];
        for (int i2 = 0; i2 < 320; ++i2) acc += zin[i2]*uw[i2*NE + e];
        lu[e] = acc;
    } else if (tid < A_ + NE + 2) {
        int g = tid - A_ - NE;
        float acc = db[g];
        for (int i2 = 0; i2 < 320; ++i2) acc += zin[i2]*dw[i2*2 + g];
        ld2[g] = acc;
    } else if (tid == 24) {
        float acc = cb[0];
        for (int h = 0; h < HD; ++h) acc += z1[h]*cw[h];
        sc[0] = acc;
    }
    __syncthreads();
    if (tid == 0) {
        float mx = la[0];
        #pragma unroll
        for (int k2 = 1; k2 < A_; ++k2) mx = fmaxf(mx, la[k2]);
        float pr[A_]; float sum = 0.f;
        #pragma unroll
        for (int k2 = 0; k2 < A_; ++k2) { pr[k2] = expf(la[k2]-mx); sum += pr[k2]; }
        const float* am = amask + ((size_t)t*N_ + n)*A_;
        float best = -1.f; int bi2 = 0;
        #pragma unroll
        for (int k2 = 0; k2 < A_; ++k2) {
            float v = pr[k2]/sum * am[k2];
            out[ob + 1 + k2] = v;
            if (v > best) { best = v; bi2 = k2; }
        }
        out[ob + 0] = (float)bi2;
    } else if (tid == 1) {
        float mx = fmaxf(fmaxf(lu[0], lu[1]), fmaxf(lu[2], lu[3]));
        float ev[NE]; float s0 = 0.f;
        #pragma unroll
        for (int e = 0; e < NE; ++e) { ev[e] = expf(lu[e]-mx); s0 += ev[e]; }
        #pragma unroll
        for (int e = 0; e < NE; ++e) uvals[e] = ev[e]/s0;
    } else if (tid == 2) {
        float mx = fmaxf(ld2[0], ld2[1]);
        float e0 = expf(ld2[0]-mx), e1 = expf(ld2[1]-mx);
        float s0 = e0 + e1;
        out[ob + 660] = e0/s0;
        out[ob + 661] = e1/s0;
        int dg = (ld2[1] > ld2[0]) ? 1 : 0;
        si[2] = dg;
        out[ob + 662] = (float)dg;
    }
    __syncthreads();
    if (tid < 128) {
        const float* Pp = Pall + ((size_t)(n*NL + si[0])*128 + tid)*NE;
        float v = Pp[0]*uvals[0] + Pp[1]*uvals[1] + Pp[2]*uvals[2] + Pp[3]*uvals[3];
        dp[tid] = v;
        out[ob + 18 + tid] = v;
    }
    __syncthreads();
    if (tid == 0) {
        int dsel;
        if (si[2] == 1) {
            float best = dp[0]; dsel = 0;
            for (int j2 = 1; j2 < 128; ++j2) if (dp[j2] > best) { best = dp[j2]; dsel = j2; }
        } else dsel = 64;
        int p = si[0];
        int pn = p + dsel - 64;
        pn = pn < 0 ? 0 : (pn > 63 ? 63 : pn);
        si[3] = pn;
        p_cur[n] = pn;
        out[ob + 17]  = (float)dsel;
        out[ob + 658] = (float)pn;
        out[ob + 659] = sc[0];
    }
    __syncthreads();
    if (tid < E_) {
        // update mp for next step (reads into zin already done, safe to overwrite)
        ((float*)mp_buf)[n*E_ + tid] = M[(n*NL + si[3])*E_ + tid];
    }
}

extern "C" void kernel_launch(void* const* d_in, const int* in_sizes, int n_in,
                              void* d_out, int out_size, void* d_ws, size_t ws_size,
                              hipStream_t stream) {
    (void)in_sizes; (void)n_in; (void)out_size; (void)ws_size;
    const int*   lines    = (const int*)  d_in[0];
    const float* obs      = (const float*)d_in[1];
    const float* invent   = (const float*)d_in[2];
    const int*   pa       = (const int*)  d_in[3];
    const float* amask    = (const float*)d_in[4];
    const int*   p0       = (const int*)  d_in[5];
    const float* emb_task = (const float*)d_in[6];
    const float* emb_low  = (const float*)d_in[7];
    const float* wi_f     = (const float*)d_in[8];
    const float* wh_f     = (const float*)d_in[9];
    const float* bi_f     = (const float*)d_in[10];
    const float* bh_f     = (const float*)d_in[11];
    const float* wi_b     = (const float*)d_in[12];
    const float* wh_b     = (const float*)d_in[13];
    const float* bi_b     = (const float*)d_in[14];
    const float* bh_b     = (const float*)d_in[15];
    const float* beta_w   = (const float*)d_in[16];
    const float* beta_b   = (const float*)d_in[17];
    const float* kernel_w = (const float*)d_in[18];
    const float* kernel_b = (const float*)d_in[19];
    const float* conv_b   = (const float*)d_in[20];
    const float* inv_w    = (const float*)d_in[21];
    const float* inv_b    = (const float*)d_in[22];
    const float* zw       = (const float*)d_in[23];
    const float* zb       = (const float*)d_in[24];
    const float* aw       = (const float*)d_in[25];
    const float* ab       = (const float*)d_in[26];
    const float* uw       = (const float*)d_in[27];
    const float* ub       = (const float*)d_in[28];
    const float* dw       = (const float*)d_in[29];
    const float* db       = (const float*)d_in[30];
    const float* cw       = (const float*)d_in[31];
    const float* cb       = (const float*)d_in[32];
    float* out = (float*)d_out;

    float* ws = (float*)d_ws;
    size_t off = 0;
    float* M        = ws + off; off += (size_t)N_*NL*E_;        // 524288
    float* wiT4     = ws + off; off += 2*32*384*4;              // 98304
    float* whT4     = ws + off; off += 2*32*384*4;              // 98304
    float* giM      = ws + off; off += (size_t)2*N_*NL*G3;      // 6291456
    float* Ball     = ws + off; off += (size_t)N_*NL*128*NE;    // 2097152
    float* Pall     = ws + off; off += (size_t)N_*NL*128*NE;    // 2097152
    float* inv_all  = ws + off; off += (size_t)T_*N_*RH;        // 131072
    float* pa_all   = ws + off; off += (size_t)T_*N_*LE;        // 131072
    float* kern_buf = ws + off; off += (size_t)N_*KCOLS;        // 589824
    float* h1_buf   = ws + off; off += (size_t)N_*CH;           // 4096
    float* mp_buf   = ws + off; off += (size_t)N_*E_;           // 8192
    int*   p_cur    = (int*)(ws + off); off += 64;

    k_prep_M<<<N_*NL, 128, 0, stream>>>(lines, emb_task, M);
    k_prep_T4<<<768, 128, 0, stream>>>(wi_f, wi_b, wh_f, wh_b, wiT4, whT4);
    k_prep_misc<<<N_, 128, 0, stream>>>(p0, M, p_cur, mp_buf);
    k_prep_invpa<<<T_*N_, 64, 0, stream>>>(invent, inv_w, inv_b, pa, emb_low, inv_all, pa_all);
    k_giM<<<dim3(8, N_, 2), 384, 0, stream>>>(M, wiT4, bi_f, bi_b, giM);
    k_gru<<<dim3(2, N_, 2), 256, 0, stream>>>(giM, whT4, bh_f, bh_b, beta_w, beta_b, Ball);
    k_P<<<N_*NL, 64, 0, stream>>>(Ball, Pall);

    for (int t = 0; t < T_; ++t) {
        k_kern<<<KCOLS/32, 256, 0, stream>>>(mp_buf, kernel_w, kernel_b, kern_buf);
        k_conv<<<dim3(8, N_), 256, 0, stream>>>(obs, kern_buf, conv_b, h1_buf, t);
        k_step2<<<N_, 256, 0, stream>>>(mp_buf, h1_buf, inv_all, pa_all, amask, Pall, M,
                                        zw, zb, aw, ab, uw, ub, dw, db, cw, cb,
                                        p_cur, out, t);
    }
}